// Round 2
// baseline (381.295 us; speedup 1.0000x reference)
//
#include <hip/hip_runtime.h>

using u16 = unsigned short;
using short8 = __attribute__((ext_vector_type(8))) short;
using floatx4 = __attribute__((ext_vector_type(4))) float;

__device__ __forceinline__ float bf2f(u16 h) {
  union { unsigned int u; float f; } v;
  v.u = ((unsigned int)h) << 16;
  return v.f;
}
__device__ __forceinline__ u16 f2bf(float f) {
  union { float f; unsigned int u; } v;
  v.f = f;
  unsigned int u = v.u;
  return (u16)((u + 0x7FFFu + ((u >> 16) & 1u)) >> 16);
}

// ---------------------------------------------------------------------------
// f32 -> bf16 (RNE) convert, vectorized x4, grid-stride
// ---------------------------------------------------------------------------
__global__ __launch_bounds__(256) void cvt_f32_bf16(
    const float* __restrict__ in, u16* __restrict__ out, int n4) {
  for (int i = blockIdx.x * blockDim.x + threadIdx.x; i < n4;
       i += gridDim.x * blockDim.x) {
    float4 v = ((const float4*)in)[i];
    ushort4 o;
    o.x = f2bf(v.x);
    o.y = f2bf(v.y);
    o.z = f2bf(v.z);
    o.w = f2bf(v.w);
    ((ushort4*)out)[i] = o;
  }
}

// ---------------------------------------------------------------------------
// NT GEMM: C[M,N] = A[M,K] @ B[N,K]^T   (A, B row-major bf16, fp32 accumulate)
// block = 256 threads = 4 waves, block tile 128x128, wave tile 64x64 (4x4 mfma)
// ---------------------------------------------------------------------------
template <int BIAS, int OUTBF16>
__global__ __launch_bounds__(256) void gemm_nt(
    const u16* __restrict__ A, const u16* __restrict__ B,
    const float* __restrict__ bias, void* __restrict__ Cout,
    int M, int N, int K) {
  const int lane = threadIdx.x & 63;
  const int wave = threadIdx.x >> 6;
  const int col = lane & 15;
  const int quad = lane >> 4;
  const int bm = blockIdx.y * 128 + (wave >> 1) * 64;
  const int bn = blockIdx.x * 128 + (wave & 1) * 64;

  floatx4 acc[4][4] = {};
  const u16* Abase = A + (size_t)(bm + col) * K + quad * 8;
  const u16* Bbase = B + (size_t)(bn + col) * K + quad * 8;

  for (int kb = 0; kb < K; kb += 32) {
    short8 af[4], bfr[4];
#pragma unroll
    for (int i = 0; i < 4; i++)
      af[i] = *(const short8*)(Abase + (size_t)i * 16 * K + kb);
#pragma unroll
    for (int i = 0; i < 4; i++)
      bfr[i] = *(const short8*)(Bbase + (size_t)i * 16 * K + kb);
#pragma unroll
    for (int mi = 0; mi < 4; mi++)
#pragma unroll
      for (int ni = 0; ni < 4; ni++)
        acc[mi][ni] = __builtin_amdgcn_mfma_f32_16x16x32_bf16(
            af[mi], bfr[ni], acc[mi][ni], 0, 0, 0);
  }

#pragma unroll
  for (int mi = 0; mi < 4; mi++) {
#pragma unroll
    for (int ni = 0; ni < 4; ni++) {
#pragma unroll
      for (int r = 0; r < 4; r++) {
        int row = bm + mi * 16 + quad * 4 + r;
        int c = bn + ni * 16 + col;
        float v = acc[mi][ni][r];
        if (BIAS) v += bias[c];
        if (OUTBF16)
          ((u16*)Cout)[(size_t)row * N + c] = f2bf(v);
        else
          ((float*)Cout)[(size_t)row * N + c] = v;
      }
    }
  }
}

// ---------------------------------------------------------------------------
// RMSNorm + rotary + relayout. One wave per (token, head); lane = dim (hd=64).
// qkv layout: [token][3*1024] with column j = which*1024 + h*64 + d (bf16).
// Writes Qb,Kb as [b][h][n][d] bf16 (Q pre-scaled by 0.125) and Vt as
// [b][h][d][n] bf16 (transposed for the PV MFMA B-operand).
// ---------------------------------------------------------------------------
__global__ __launch_bounds__(256) void rope_norm(
    const u16* __restrict__ qkv, const float* __restrict__ qw,
    const float* __restrict__ kw, const float* __restrict__ pcos,
    const float* __restrict__ psin, u16* __restrict__ Qb,
    u16* __restrict__ Kb, u16* __restrict__ Vt) {
  const int w = blockIdx.x * 4 + (threadIdx.x >> 6);  // (t,h) id: 0..65535
  const int lane = threadIdx.x & 63;
  const int t = w >> 4;
  const int h = w & 15;
  const int n = t & 2047;
  const int b = t >> 11;

  const u16* base = qkv + (size_t)t * 3072 + h * 64 + lane;
  float qv = bf2f(base[0]);
  float kv = bf2f(base[1024]);
  float vv = bf2f(base[2048]);

  float sq = qv * qv, sk = kv * kv;
#pragma unroll
  for (int off = 32; off; off >>= 1) {
    sq += __shfl_xor(sq, off);
    sk += __shfl_xor(sk, off);
  }
  float qn = qv * rsqrtf(sq * (1.0f / 64.0f) + 1e-6f) * qw[lane];
  float kn = kv * rsqrtf(sk * (1.0f / 64.0f) + 1e-6f) * kw[lane];

  const int i = lane >> 1;
  const float c = pcos[n * 32 + i];
  const float s = psin[n * 32 + i];
  float qp = __shfl_xor(qn, 1);
  float kp = __shfl_xor(kn, 1);
  float qr, kr;
  if (lane & 1) {  // odd lane holds ti; partner holds tr
    qr = qp * s + qn * c;
    kr = kp * s + kn * c;
  } else {  // even lane holds tr; partner holds ti
    qr = qn * c - qp * s;
    kr = kn * c - kp * s;
  }
  qr *= 0.125f;  // fold attention scale hd^-0.5 into Q (exact in bf16)

  const size_t o = ((size_t)(b * 16 + h) * 2048 + n) * 64 + lane;
  Qb[o] = f2bf(qr);
  Kb[o] = f2bf(kr);
  Vt[((size_t)(b * 16 + h) * 64 + lane) * 2048 + n] = f2bf(vv);
}

// ---------------------------------------------------------------------------
// Flash attention (causal). One wave (block=64) per (b*h, 16-row Q tile).
// Key steps of 32. QK^T: 4 MFMA; softmax in C-layout (row=quad*4+r,
// col=lane&15, 16-lane shfl reductions); P C->A layout via LDS; PV: 4 MFMA
// with Vt b-frags (contiguous along keys). O accumulated fp32 in C-layout.
// ---------------------------------------------------------------------------
__global__ __launch_bounds__(64) void attn_flash(
    const u16* __restrict__ Q, const u16* __restrict__ Kk,
    const u16* __restrict__ Vt, u16* __restrict__ O) {
  __shared__ u16 Pb[16 * 32];
  const int bh = blockIdx.x;         // b*16 + h
  const int q0 = blockIdx.y * 16;
  const int lane = threadIdx.x;
  const int col = lane & 15;
  const int quad = lane >> 4;

  const u16* Qh = Q + (size_t)bh * 2048 * 64;
  const u16* Kh = Kk + (size_t)bh * 2048 * 64;
  const u16* Vh = Vt + (size_t)bh * 64 * 2048;

  short8 aq[2];
#pragma unroll
  for (int ks = 0; ks < 2; ks++)
    aq[ks] = *(const short8*)(Qh + (size_t)(q0 + col) * 64 + ks * 32 + quad * 8);

  float m[4], l[4];
  floatx4 accO[4] = {};
#pragma unroll
  for (int r = 0; r < 4; r++) { m[r] = -1e30f; l[r] = 0.0f; }

  const int ktmax = (q0 + 15) >> 5;
  for (int kt = 0; kt <= ktmax; kt++) {
    const int j0 = kt * 32;
    floatx4 s[2] = {};
#pragma unroll
    for (int nt = 0; nt < 2; nt++) {
#pragma unroll
      for (int ks = 0; ks < 2; ks++) {
        short8 bk = *(const short8*)(Kh + (size_t)(j0 + nt * 16 + col) * 64 +
                                     ks * 32 + quad * 8);
        s[nt] = __builtin_amdgcn_mfma_f32_16x16x32_bf16(aq[ks], bk, s[nt], 0, 0, 0);
      }
    }

    float alpha[4];
#pragma unroll
    for (int r = 0; r < 4; r++) {
      const int qg = q0 + quad * 4 + r;
#pragma unroll
      for (int nt = 0; nt < 2; nt++) {
        int jg = j0 + nt * 16 + col;
        if (jg > qg) s[nt][r] = -1e30f;
      }
      float rm = fmaxf(s[0][r], s[1][r]);
#pragma unroll
      for (int off = 8; off; off >>= 1) rm = fmaxf(rm, __shfl_xor(rm, off));
      float mnew = fmaxf(m[r], rm);
      alpha[r] = __expf(m[r] - mnew);
      float p0 = __expf(s[0][r] - mnew);
      float p1 = __expf(s[1][r] - mnew);
      s[0][r] = p0;
      s[1][r] = p1;
      float prs = p0 + p1;
#pragma unroll
      for (int off = 8; off; off >>= 1) prs += __shfl_xor(prs, off);
      l[r] = l[r] * alpha[r] + prs;
      m[r] = mnew;
    }
#pragma unroll
    for (int nt = 0; nt < 4; nt++)
#pragma unroll
      for (int r = 0; r < 4; r++) accO[nt][r] *= alpha[r];

    // P: C-layout -> A-layout via LDS round-trip (bf16)
    __syncthreads();  // prior iteration's read done before overwrite
#pragma unroll
    for (int nt = 0; nt < 2; nt++)
#pragma unroll
      for (int r = 0; r < 4; r++)
        Pb[(quad * 4 + r) * 32 + nt * 16 + col] = f2bf(s[nt][r]);
    __syncthreads();
    short8 ap = *(const short8*)(Pb + col * 32 + quad * 8);

#pragma unroll
    for (int nt = 0; nt < 4; nt++) {
      short8 bv = *(const short8*)(Vh + (size_t)(nt * 16 + col) * 2048 + j0 +
                                   quad * 8);
      accO[nt] = __builtin_amdgcn_mfma_f32_16x16x32_bf16(ap, bv, accO[nt], 0, 0, 0);
    }
  }

  // epilogue: O token-major [b][n][h][d] so it feeds the proj GEMM directly
  const int b = bh >> 4;
  const int h = bh & 15;
#pragma unroll
  for (int nt = 0; nt < 4; nt++) {
#pragma unroll
    for (int r = 0; r < 4; r++) {
      int qg = q0 + quad * 4 + r;
      int d = nt * 16 + col;
      O[((size_t)(b * 2048 + qg) * 16 + h) * 64 + d] = f2bf(accO[nt][r] / l[r]);
    }
  }
}

// ---------------------------------------------------------------------------
extern "C" void kernel_launch(void* const* d_in, const int* in_sizes, int n_in,
                              void* d_out, int out_size, void* d_ws,
                              size_t ws_size, hipStream_t stream) {
  const float* x = (const float*)d_in[0];        // [2,2048,1024] f32
  const float* qkv_w = (const float*)d_in[1];    // [3072,1024] f32
  const float* q_norm_w = (const float*)d_in[2]; // [64] f32
  const float* k_norm_w = (const float*)d_in[3]; // [64] f32
  const float* proj_w = (const float*)d_in[4];   // [1024,1024] f32
  const float* proj_b = (const float*)d_in[5];   // [1024] f32
  const float* pos_cos = (const float*)d_in[6];  // [2048,32] f32
  const float* pos_sin = (const float*)d_in[7];  // [2048,32] f32
  // d_in[8] = causal mask: known analytically, ignored

  char* ws = (char*)d_ws;
  u16* xb = (u16*)ws;                          //  8 MB (4096*1024 bf16)
  u16* wqkvb = (u16*)(ws + 8388608);           //  6 MB (3072*1024 bf16)
  u16* wprojb = (u16*)(ws + 14680064);         //  2 MB (1024*1024 bf16)
  u16* qkv = (u16*)(ws + 16777216);            // 24 MB (4096*3072 bf16)
  u16* Qb = (u16*)(ws + 41943040);             //  8 MB
  u16* Kb = (u16*)(ws + 50331648);             //  8 MB
  u16* Vt = (u16*)(ws + 58720256);             //  8 MB
  u16* AO = (u16*)(ws + 67108864);             //  8 MB  (total 72 MB)

  // 0) f32 -> bf16 conversions
  cvt_f32_bf16<<<2048, 256, 0, stream>>>(x, xb, 4096 * 1024 / 4);
  cvt_f32_bf16<<<1536, 256, 0, stream>>>(qkv_w, wqkvb, 3072 * 1024 / 4);
  cvt_f32_bf16<<<512, 256, 0, stream>>>(proj_w, wprojb, 1024 * 1024 / 4);

  // 1) qkv = x @ qkv_w^T   (M=4096, N=3072, K=1024), bf16 out
  gemm_nt<0, 1><<<dim3(3072 / 128, 4096 / 128), 256, 0, stream>>>(
      xb, wqkvb, nullptr, qkv, 4096, 3072, 1024);

  // 2) rmsnorm + rotary + relayout (65536 (t,h) waves)
  rope_norm<<<65536 / 4, 256, 0, stream>>>(qkv, q_norm_w, k_norm_w, pos_cos,
                                           pos_sin, Qb, Kb, Vt);

  // 3) causal flash attention: 32 (b,h) x 128 q-tiles, one wave each
  attn_flash<<<dim3(32, 128), 64, 0, stream>>>(Qb, Kb, Vt, AO);

  // 4) out = AO @ proj_w^T + proj_b  (M=4096, N=1024, K=1024), f32 out
  gemm_nt<1, 0><<<dim3(1024 / 128, 4096 / 128), 256, 0, stream>>>(
      AO, wprojb, proj_b, (float*)d_out, 4096, 1024, 1024);
}

// Round 3
// 370.907 us; speedup vs baseline: 1.0280x; 1.0280x over previous
//
#include <hip/hip_runtime.h>

using u16 = unsigned short;
using short8 = __attribute__((ext_vector_type(8))) short;
using floatx4 = __attribute__((ext_vector_type(4))) float;

__device__ __forceinline__ float bf2f(u16 h) {
  union { unsigned int u; float f; } v;
  v.u = ((unsigned int)h) << 16;
  return v.f;
}
__device__ __forceinline__ u16 f2bf(float f) {
  union { float f; unsigned int u; } v;
  v.f = f;
  unsigned int u = v.u;
  return (u16)((u + 0x7FFFu + ((u >> 16) & 1u)) >> 16);
}

// ---------------------------------------------------------------------------
// f32 -> bf16 (RNE) convert, vectorized x4, grid-stride
// ---------------------------------------------------------------------------
__global__ __launch_bounds__(256) void cvt_f32_bf16(
    const float* __restrict__ in, u16* __restrict__ out, int n4) {
  for (int i = blockIdx.x * blockDim.x + threadIdx.x; i < n4;
       i += gridDim.x * blockDim.x) {
    float4 v = ((const float4*)in)[i];
    ushort4 o;
    o.x = f2bf(v.x);
    o.y = f2bf(v.y);
    o.z = f2bf(v.z);
    o.w = f2bf(v.w);
    ((ushort4*)out)[i] = o;
  }
}

// ---------------------------------------------------------------------------
// NT GEMM: C[M,N] = A[M,K] @ B[N,K]^T   (A, B row-major bf16, fp32 accumulate)
// block = 256 threads = 4 waves, block tile 128x128, wave tile 64x64 (4x4 mfma)
// ---------------------------------------------------------------------------
template <int BIAS, int OUTBF16>
__global__ __launch_bounds__(256) void gemm_nt(
    const u16* __restrict__ A, const u16* __restrict__ B,
    const float* __restrict__ bias, void* __restrict__ Cout,
    int M, int N, int K) {
  const int lane = threadIdx.x & 63;
  const int wave = threadIdx.x >> 6;
  const int col = lane & 15;
  const int quad = lane >> 4;
  const int bm = blockIdx.y * 128 + (wave >> 1) * 64;
  const int bn = blockIdx.x * 128 + (wave & 1) * 64;

  floatx4 acc[4][4] = {};
  const u16* Abase = A + (size_t)(bm + col) * K + quad * 8;
  const u16* Bbase = B + (size_t)(bn + col) * K + quad * 8;

  for (int kb = 0; kb < K; kb += 32) {
    short8 af[4], bfr[4];
#pragma unroll
    for (int i = 0; i < 4; i++)
      af[i] = *(const short8*)(Abase + (size_t)i * 16 * K + kb);
#pragma unroll
    for (int i = 0; i < 4; i++)
      bfr[i] = *(const short8*)(Bbase + (size_t)i * 16 * K + kb);
#pragma unroll
    for (int mi = 0; mi < 4; mi++)
#pragma unroll
      for (int ni = 0; ni < 4; ni++)
        acc[mi][ni] = __builtin_amdgcn_mfma_f32_16x16x32_bf16(
            af[mi], bfr[ni], acc[mi][ni], 0, 0, 0);
  }

#pragma unroll
  for (int mi = 0; mi < 4; mi++) {
#pragma unroll
    for (int ni = 0; ni < 4; ni++) {
#pragma unroll
      for (int r = 0; r < 4; r++) {
        int row = bm + mi * 16 + quad * 4 + r;
        int c = bn + ni * 16 + col;
        float v = acc[mi][ni][r];
        if (BIAS) v += bias[c];
        if (OUTBF16)
          ((u16*)Cout)[(size_t)row * N + c] = f2bf(v);
        else
          ((float*)Cout)[(size_t)row * N + c] = v;
      }
    }
  }
}

// ---------------------------------------------------------------------------
// RMSNorm + rotary + relayout. One wave per (token, head); lane = dim (hd=64).
// ---------------------------------------------------------------------------
__global__ __launch_bounds__(256) void rope_norm(
    const u16* __restrict__ qkv, const float* __restrict__ qw,
    const float* __restrict__ kw, const float* __restrict__ pcos,
    const float* __restrict__ psin, u16* __restrict__ Qb,
    u16* __restrict__ Kb, u16* __restrict__ Vt) {
  const int w = blockIdx.x * 4 + (threadIdx.x >> 6);  // (t,h) id: 0..65535
  const int lane = threadIdx.x & 63;
  const int t = w >> 4;
  const int h = w & 15;
  const int n = t & 2047;
  const int b = t >> 11;

  const u16* base = qkv + (size_t)t * 3072 + h * 64 + lane;
  float qv = bf2f(base[0]);
  float kv = bf2f(base[1024]);
  float vv = bf2f(base[2048]);

  float sq = qv * qv, sk = kv * kv;
#pragma unroll
  for (int off = 32; off; off >>= 1) {
    sq += __shfl_xor(sq, off);
    sk += __shfl_xor(sk, off);
  }
  float qn = qv * rsqrtf(sq * (1.0f / 64.0f) + 1e-6f) * qw[lane];
  float kn = kv * rsqrtf(sk * (1.0f / 64.0f) + 1e-6f) * kw[lane];

  const int i = lane >> 1;
  const float c = pcos[n * 32 + i];
  const float s = psin[n * 32 + i];
  float qp = __shfl_xor(qn, 1);
  float kp = __shfl_xor(kn, 1);
  float qr, kr;
  if (lane & 1) {
    qr = qp * s + qn * c;
    kr = kp * s + kn * c;
  } else {
    qr = qn * c - qp * s;
    kr = kn * c - kp * s;
  }
  qr *= 0.125f;  // fold attention scale hd^-0.5 into Q (exact in bf16)

  const size_t o = ((size_t)(b * 16 + h) * 2048 + n) * 64 + lane;
  Qb[o] = f2bf(qr);
  Kb[o] = f2bf(kr);
  Vt[((size_t)(b * 16 + h) * 64 + lane) * 2048 + n] = f2bf(vv);
}

// ---------------------------------------------------------------------------
// Flash attention v2 (causal). One wave per (bh, tile-pair). Each wave does
// q-tiles p and 127-p (uniform 33 steps of 64 keys). Fixed-max softmax:
// scores bounded by |s|<=8.1 (rmsnorm + 0.125 scale), so p=exp(s-16) needs
// no running max, no alpha rescale; l is lane-partial, reduced once at end.
// Pb stride 68 (u16) makes the C->A layout LDS write conflict-free.
// ---------------------------------------------------------------------------
__global__ __launch_bounds__(64) void attn_flash(
    const u16* __restrict__ Q, const u16* __restrict__ Kk,
    const u16* __restrict__ Vt, u16* __restrict__ O) {
  __shared__ u16 Pb[16 * 68];
  const int bh = blockIdx.x;   // b*16 + h
  const int pr = blockIdx.y;   // pair index 0..63
  const int lane = threadIdx.x;
  const int col = lane & 15;
  const int quad = lane >> 4;

  const u16* Qh = Q + (size_t)bh * 2048 * 64;
  const u16* Kh = Kk + (size_t)bh * 2048 * 64;
  const u16* Vh = Vt + (size_t)bh * 64 * 2048;
  const int b = bh >> 4;
  const int h = bh & 15;

  for (int t = 0; t < 2; t++) {
    const int q0 = (t ? (127 - pr) : pr) * 16;

    short8 aq[2];
#pragma unroll
    for (int ks = 0; ks < 2; ks++)
      aq[ks] = *(const short8*)(Qh + (size_t)(q0 + col) * 64 + ks * 32 + quad * 8);

    floatx4 accO[4] = {};
    float l[4] = {0.f, 0.f, 0.f, 0.f};
    const int nsteps = q0 / 64 + 1;

    for (int kt = 0; kt < nsteps; kt++) {
      const int j0 = kt * 64;

      // S = Q K^T : 8 MFMA covering 16 q x 64 keys
      floatx4 s[4] = {};
#pragma unroll
      for (int nt = 0; nt < 4; nt++) {
#pragma unroll
        for (int ks = 0; ks < 2; ks++) {
          short8 bk = *(const short8*)(Kh + (size_t)(j0 + nt * 16 + col) * 64 +
                                       ks * 32 + quad * 8);
          s[nt] = __builtin_amdgcn_mfma_f32_16x16x32_bf16(aq[ks], bk, s[nt], 0, 0, 0);
        }
      }

      // p = exp(s - 16) with causal mask; lane-partial row sums; P -> LDS
      __syncthreads();  // prior iteration's Pb read done before overwrite
#pragma unroll
      for (int nt = 0; nt < 4; nt++) {
        const int jg = j0 + nt * 16 + col;
#pragma unroll
        for (int r = 0; r < 4; r++) {
          const int qg = q0 + quad * 4 + r;
          float pv = (jg <= qg) ? __expf(s[nt][r] - 16.0f) : 0.0f;
          l[r] += pv;
          Pb[(quad * 4 + r) * 68 + nt * 16 + col] = f2bf(pv);
        }
      }
      __syncthreads();

      // P in A-layout; V^T frags contiguous along keys; 8 MFMA for PV
      short8 ap[2];
#pragma unroll
      for (int kf = 0; kf < 2; kf++)
        ap[kf] = *(const short8*)(Pb + col * 68 + kf * 32 + quad * 8);
#pragma unroll
      for (int nt = 0; nt < 4; nt++) {
#pragma unroll
        for (int kf = 0; kf < 2; kf++) {
          short8 bv = *(const short8*)(Vh + (size_t)(nt * 16 + col) * 2048 +
                                       j0 + kf * 32 + quad * 8);
          accO[nt] = __builtin_amdgcn_mfma_f32_16x16x32_bf16(ap[kf], bv, accO[nt], 0, 0, 0);
        }
      }
    }

    // final row-sum reduction across the 16 cols
#pragma unroll
    for (int r = 0; r < 4; r++) {
#pragma unroll
      for (int off = 8; off; off >>= 1) l[r] += __shfl_xor(l[r], off);
    }

    // epilogue: O token-major [b][n][h][d] feeding the proj GEMM
#pragma unroll
    for (int nt = 0; nt < 4; nt++) {
#pragma unroll
      for (int r = 0; r < 4; r++) {
        int qg = q0 + quad * 4 + r;
        int d = nt * 16 + col;
        O[((size_t)(b * 2048 + qg) * 16 + h) * 64 + d] = f2bf(accO[nt][r] / l[r]);
      }
    }
  }
}

// ---------------------------------------------------------------------------
extern "C" void kernel_launch(void* const* d_in, const int* in_sizes, int n_in,
                              void* d_out, int out_size, void* d_ws,
                              size_t ws_size, hipStream_t stream) {
  const float* x = (const float*)d_in[0];        // [2,2048,1024] f32
  const float* qkv_w = (const float*)d_in[1];    // [3072,1024] f32
  const float* q_norm_w = (const float*)d_in[2]; // [64] f32
  const float* k_norm_w = (const float*)d_in[3]; // [64] f32
  const float* proj_w = (const float*)d_in[4];   // [1024,1024] f32
  const float* proj_b = (const float*)d_in[5];   // [1024] f32
  const float* pos_cos = (const float*)d_in[6];  // [2048,32] f32
  const float* pos_sin = (const float*)d_in[7];  // [2048,32] f32
  // d_in[8] = causal mask: known analytically, ignored

  char* ws = (char*)d_ws;
  u16* xb = (u16*)ws;                          //  8 MB (4096*1024 bf16)
  u16* wqkvb = (u16*)(ws + 8388608);           //  6 MB (3072*1024 bf16)
  u16* wprojb = (u16*)(ws + 14680064);         //  2 MB (1024*1024 bf16)
  u16* qkv = (u16*)(ws + 16777216);            // 24 MB (4096*3072 bf16)
  u16* Qb = (u16*)(ws + 41943040);             //  8 MB
  u16* Kb = (u16*)(ws + 50331648);             //  8 MB
  u16* Vt = (u16*)(ws + 58720256);             //  8 MB
  u16* AO = (u16*)(ws + 67108864);             //  8 MB  (total 72 MB)

  // 0) f32 -> bf16 conversions
  cvt_f32_bf16<<<2048, 256, 0, stream>>>(x, xb, 4096 * 1024 / 4);
  cvt_f32_bf16<<<1536, 256, 0, stream>>>(qkv_w, wqkvb, 3072 * 1024 / 4);
  cvt_f32_bf16<<<512, 256, 0, stream>>>(proj_w, wprojb, 1024 * 1024 / 4);

  // 1) qkv = x @ qkv_w^T   (M=4096, N=3072, K=1024), bf16 out
  gemm_nt<0, 1><<<dim3(3072 / 128, 4096 / 128), 256, 0, stream>>>(
      xb, wqkvb, nullptr, qkv, 4096, 3072, 1024);

  // 2) rmsnorm + rotary + relayout (65536 (t,h) waves)
  rope_norm<<<65536 / 4, 256, 0, stream>>>(qkv, q_norm_w, k_norm_w, pos_cos,
                                           pos_sin, Qb, Kb, Vt);

  // 3) causal flash attention v2: 32 bh x 64 balanced tile-pairs, one wave each
  attn_flash<<<dim3(32, 64), 64, 0, stream>>>(Qb, Kb, Vt, AO);

  // 4) out = AO @ proj_w^T + proj_b  (M=4096, N=1024, K=1024), f32 out
  gemm_nt<1, 0><<<dim3(1024 / 128, 4096 / 128), 256, 0, stream>>>(
      AO, wprojb, proj_b, (float*)d_out, 4096, 1024, 1024);
}

// Round 4
// 233.207 us; speedup vs baseline: 1.6350x; 1.5905x over previous
//
#include <hip/hip_runtime.h>

using u16 = unsigned short;
using short8 = __attribute__((ext_vector_type(8))) short;
using floatx4 = __attribute__((ext_vector_type(4))) float;

__device__ __forceinline__ float bf2f(u16 h) {
  union { unsigned int u; float f; } v;
  v.u = ((unsigned int)h) << 16;
  return v.f;
}
__device__ __forceinline__ u16 f2bf(float f) {
  union { float f; unsigned int u; } v;
  v.f = f;
  unsigned int u = v.u;
  return (u16)((u + 0x7FFFu + ((u >> 16) & 1u)) >> 16);
}

// async global->LDS 16B copy (dest must be uniform base + lane*16)
typedef const __attribute__((address_space(1))) unsigned int* gas_t;
typedef __attribute__((address_space(3))) unsigned int* las_t;
__device__ __forceinline__ void gl_lds16(const u16* g, u16* l) {
  __builtin_amdgcn_global_load_lds((gas_t)(const void*)g, (las_t)(void*)l, 16,
                                   0, 0);
}

// ---------------------------------------------------------------------------
// f32 -> bf16 (RNE) convert, vectorized x4, grid-stride
// ---------------------------------------------------------------------------
__global__ __launch_bounds__(256) void cvt_f32_bf16(
    const float* __restrict__ in, u16* __restrict__ out, int n4) {
  for (int i = blockIdx.x * blockDim.x + threadIdx.x; i < n4;
       i += gridDim.x * blockDim.x) {
    float4 v = ((const float4*)in)[i];
    ushort4 o;
    o.x = f2bf(v.x);
    o.y = f2bf(v.y);
    o.z = f2bf(v.z);
    o.w = f2bf(v.w);
    ((ushort4*)out)[i] = o;
  }
}

// ---------------------------------------------------------------------------
// NT GEMM, m97 structure: C[M,N] = A[M,K] @ B[N,K]^T, bf16 in, fp32 acc.
// 128x128 block tile, BK=32, global_load_lds(16B) staging, 4 waves,
// wave tile 64x64 = 4x4 x mfma_16x16x32.
// ---------------------------------------------------------------------------
template <int BIAS, int OUTBF16>
__global__ __launch_bounds__(256) void gemm_nt(
    const u16* __restrict__ A, const u16* __restrict__ B,
    const float* __restrict__ bias, void* __restrict__ Cout,
    int M, int N, int K) {
  __shared__ u16 As[128 * 32];
  __shared__ u16 Bs[128 * 32];
  const int tid = threadIdx.x;
  const int lane = tid & 63;
  const int wave = tid >> 6;
  const int col = lane & 15;
  const int quad = lane >> 4;
  const int bm = blockIdx.y * 128;
  const int bn = blockIdx.x * 128;
  const int wm = (wave >> 1) * 64;
  const int wn = (wave & 1) * 64;

  floatx4 acc[4][4] = {};

  for (int kb = 0; kb < K; kb += 32) {
    __syncthreads();  // previous fragment reads done
#pragma unroll
    for (int i = 0; i < 2; i++) {
      const int c = i * 256 + tid;      // chunk: row=c>>2, 16B piece=c&3
      const int row = c >> 2;
      const int kc = (c & 3) * 8;
      gl_lds16(A + (size_t)(bm + row) * K + kb + kc, (u16*)As + c * 8);
      gl_lds16(B + (size_t)(bn + row) * K + kb + kc, (u16*)Bs + c * 8);
    }
    __syncthreads();  // fills visible

    short8 af[4], bfr[4];
#pragma unroll
    for (int i = 0; i < 4; i++)
      af[i] = *(const short8*)(As + (wm + i * 16 + col) * 32 + quad * 8);
#pragma unroll
    for (int i = 0; i < 4; i++)
      bfr[i] = *(const short8*)(Bs + (wn + i * 16 + col) * 32 + quad * 8);
#pragma unroll
    for (int mi = 0; mi < 4; mi++)
#pragma unroll
      for (int ni = 0; ni < 4; ni++)
        acc[mi][ni] = __builtin_amdgcn_mfma_f32_16x16x32_bf16(
            af[mi], bfr[ni], acc[mi][ni], 0, 0, 0);
  }

#pragma unroll
  for (int mi = 0; mi < 4; mi++) {
#pragma unroll
    for (int ni = 0; ni < 4; ni++) {
#pragma unroll
      for (int r = 0; r < 4; r++) {
        int row = bm + wm + mi * 16 + quad * 4 + r;
        int c = bn + wn + ni * 16 + col;
        float v = acc[mi][ni][r];
        if (BIAS) v += bias[c];
        if (OUTBF16)
          ((u16*)Cout)[(size_t)row * N + c] = f2bf(v);
        else
          ((float*)Cout)[(size_t)row * N + c] = v;
      }
    }
  }
}

// ---------------------------------------------------------------------------
// RMSNorm + rotary for Q,K only. One wave per (token, head); lane = dim.
// ---------------------------------------------------------------------------
__global__ __launch_bounds__(256) void rope_norm(
    const u16* __restrict__ qkv, const float* __restrict__ qw,
    const float* __restrict__ kw, const float* __restrict__ pcos,
    const float* __restrict__ psin, u16* __restrict__ Qb,
    u16* __restrict__ Kb) {
  const int w = blockIdx.x * 4 + (threadIdx.x >> 6);  // (t,h) id: 0..65535
  const int lane = threadIdx.x & 63;
  const int t = w >> 4;
  const int h = w & 15;
  const int n = t & 2047;
  const int b = t >> 11;

  const u16* base = qkv + (size_t)t * 3072 + h * 64 + lane;
  float qv = bf2f(base[0]);
  float kv = bf2f(base[1024]);

  float sq = qv * qv, sk = kv * kv;
#pragma unroll
  for (int off = 32; off; off >>= 1) {
    sq += __shfl_xor(sq, off);
    sk += __shfl_xor(sk, off);
  }
  float qn = qv * rsqrtf(sq * (1.0f / 64.0f) + 1e-6f) * qw[lane];
  float kn = kv * rsqrtf(sk * (1.0f / 64.0f) + 1e-6f) * kw[lane];

  const int i = lane >> 1;
  const float c = pcos[n * 32 + i];
  const float s = psin[n * 32 + i];
  float qp = __shfl_xor(qn, 1);
  float kp = __shfl_xor(kn, 1);
  float qr, kr;
  if (lane & 1) {
    qr = qp * s + qn * c;
    kr = kp * s + kn * c;
  } else {
    qr = qn * c - qp * s;
    kr = kn * c - kp * s;
  }
  qr *= 0.125f;  // fold attention scale hd^-0.5 into Q

  const size_t o = ((size_t)(b * 16 + h) * 2048 + n) * 64 + lane;
  Qb[o] = f2bf(qr);
  Kb[o] = f2bf(kr);
}

// ---------------------------------------------------------------------------
// V transpose: qkv V-slice [token][d] -> Vt [bh][d][n], 64x64 LDS tiles,
// coalesced 128B rows both directions.
// ---------------------------------------------------------------------------
__global__ __launch_bounds__(256) void vtrans(const u16* __restrict__ qkv,
                                              u16* __restrict__ Vt) {
  __shared__ u16 T[64 * 68];
  const int bh = blockIdx.x;  // b*16+h
  const int n0 = blockIdx.y * 64;
  const int b = bh >> 4, h = bh & 15;
  const int tid = threadIdx.x;
  const int q = tid & 7;   // 16B chunk within a 128B row
  const int r = tid >> 3;  // 0..31

#pragma unroll
  for (int rr = r; rr < 64; rr += 32) {
    short8 v = *(const short8*)(qkv + (size_t)(b * 2048 + n0 + rr) * 3072 +
                                2048 + h * 64 + q * 8);
    *(short8*)&T[rr * 68 + q * 8] = v;
  }
  __syncthreads();
#pragma unroll
  for (int dd = r; dd < 64; dd += 32) {
    short8 o;
#pragma unroll
    for (int j = 0; j < 8; j++) o[j] = T[(q * 8 + j) * 68 + dd];
    *(short8*)(Vt + (size_t)(bh * 64 + dd) * 2048 + n0 + q * 8) = o;
  }
}

// ---------------------------------------------------------------------------
// Flash attention v3 (causal). Block = 4 waves = 64 q-rows; balanced tile
// pairs (tile pr and 31-pr, 33 x 64-key steps total). K/V staged in LDS via
// global_load_lds in 32-dim halves (64B rows). Fixed-max softmax
// (|s|<=8.1 after rmsnorm+0.125 scale): p=exp(s-16), no running max.
// ---------------------------------------------------------------------------
__global__ __launch_bounds__(256) void attn_flash(
    const u16* __restrict__ Q, const u16* __restrict__ Kk,
    const u16* __restrict__ Vt, u16* __restrict__ O) {
  __shared__ u16 Ks[2][64 * 32];  // [d-half][key][32d]
  __shared__ u16 Vs[2][64 * 32];  // [key-half][d][32keys]
  __shared__ u16 Pb[4][16 * 68];  // per-wave P round-trip
  const int bh = blockIdx.x;
  const int pr = blockIdx.y;  // 0..15
  const int tid = threadIdx.x;
  const int lane = tid & 63;
  const int wave = tid >> 6;
  const int col = lane & 15;
  const int quad = lane >> 4;
  const int srow = tid >> 2;     // staging: row 0..63
  const int spc = (tid & 3) * 8; // staging: 16B piece

  const u16* Qh = Q + (size_t)bh * 2048 * 64;
  const u16* Kh = Kk + (size_t)bh * 2048 * 64;
  const u16* Vh = Vt + (size_t)bh * 64 * 2048;
  const int b = bh >> 4, h = bh & 15;

  for (int t = 0; t < 2; t++) {
    const int tile = t ? (31 - pr) : pr;
    const int q0 = tile * 64 + wave * 16;  // this wave's 16 q-rows

    short8 aq[2];
#pragma unroll
    for (int ks = 0; ks < 2; ks++)
      aq[ks] =
          *(const short8*)(Qh + (size_t)(q0 + col) * 64 + ks * 32 + quad * 8);

    floatx4 accO[4] = {};
    float l[4] = {0.f, 0.f, 0.f, 0.f};
    const int nsteps = tile + 1;

    for (int kt = 0; kt < nsteps; kt++) {
      const int j0 = kt * 64;
      __syncthreads();  // prior step's K/V/P reads done (all waves)
#pragma unroll
      for (int half = 0; half < 2; half++) {
        gl_lds16(Kh + (size_t)(j0 + srow) * 64 + half * 32 + spc,
                 &Ks[half][0] + tid * 8);
        gl_lds16(Vh + (size_t)srow * 2048 + j0 + half * 32 + spc,
                 &Vs[half][0] + tid * 8);
      }
      __syncthreads();  // fills visible

      // S = Q K^T : 8 MFMA covering 16 q x 64 keys
      floatx4 s[4] = {};
#pragma unroll
      for (int nt = 0; nt < 4; nt++) {
#pragma unroll
        for (int ks = 0; ks < 2; ks++) {
          short8 bk =
              *(const short8*)&Ks[ks][(nt * 16 + col) * 32 + quad * 8];
          s[nt] =
              __builtin_amdgcn_mfma_f32_16x16x32_bf16(aq[ks], bk, s[nt], 0, 0, 0);
        }
      }

      // p = exp(s-16) + causal mask; lane-partial row sums; P -> LDS
#pragma unroll
      for (int nt = 0; nt < 4; nt++) {
        const int jg = j0 + nt * 16 + col;
#pragma unroll
        for (int r = 0; r < 4; r++) {
          const int qg = q0 + quad * 4 + r;
          float pv = (jg <= qg) ? __expf(s[nt][r] - 16.0f) : 0.0f;
          l[r] += pv;
          Pb[wave][(quad * 4 + r) * 68 + nt * 16 + col] = f2bf(pv);
        }
      }
      __syncthreads();  // P visible (and V still valid)

      short8 ap[2];
#pragma unroll
      for (int kf = 0; kf < 2; kf++)
        ap[kf] = *(const short8*)&Pb[wave][col * 68 + kf * 32 + quad * 8];
#pragma unroll
      for (int nt = 0; nt < 4; nt++) {
#pragma unroll
        for (int kf = 0; kf < 2; kf++) {
          short8 bv =
              *(const short8*)&Vs[kf][(nt * 16 + col) * 32 + quad * 8];
          accO[nt] = __builtin_amdgcn_mfma_f32_16x16x32_bf16(ap[kf], bv,
                                                             accO[nt], 0, 0, 0);
        }
      }
    }

    // final row-sum reduction across the 16 cols
#pragma unroll
    for (int r = 0; r < 4; r++) {
#pragma unroll
      for (int off = 8; off; off >>= 1) l[r] += __shfl_xor(l[r], off);
    }

    // epilogue: O token-major [b][n][h][d] feeding the proj GEMM
#pragma unroll
    for (int nt = 0; nt < 4; nt++) {
#pragma unroll
      for (int r = 0; r < 4; r++) {
        int qg = q0 + quad * 4 + r;
        int d = nt * 16 + col;
        O[((size_t)(b * 2048 + qg) * 16 + h) * 64 + d] = f2bf(accO[nt][r] / l[r]);
      }
    }
  }
}

// ---------------------------------------------------------------------------
extern "C" void kernel_launch(void* const* d_in, const int* in_sizes, int n_in,
                              void* d_out, int out_size, void* d_ws,
                              size_t ws_size, hipStream_t stream) {
  const float* x = (const float*)d_in[0];        // [2,2048,1024] f32
  const float* qkv_w = (const float*)d_in[1];    // [3072,1024] f32
  const float* q_norm_w = (const float*)d_in[2]; // [64] f32
  const float* k_norm_w = (const float*)d_in[3]; // [64] f32
  const float* proj_w = (const float*)d_in[4];   // [1024,1024] f32
  const float* proj_b = (const float*)d_in[5];   // [1024] f32
  const float* pos_cos = (const float*)d_in[6];  // [2048,32] f32
  const float* pos_sin = (const float*)d_in[7];  // [2048,32] f32
  // d_in[8] = causal mask: known analytically, ignored

  char* ws = (char*)d_ws;
  u16* xb = (u16*)ws;                          //  8 MB (4096*1024 bf16)
  u16* wqkvb = (u16*)(ws + 8388608);           //  6 MB (3072*1024 bf16)
  u16* wprojb = (u16*)(ws + 14680064);         //  2 MB (1024*1024 bf16)
  u16* qkv = (u16*)(ws + 16777216);            // 24 MB (4096*3072 bf16)
  u16* Qb = (u16*)(ws + 41943040);             //  8 MB
  u16* Kb = (u16*)(ws + 50331648);             //  8 MB
  u16* Vt = (u16*)(ws + 58720256);             //  8 MB
  u16* AO = (u16*)(ws + 67108864);             //  8 MB  (total 72 MB)

  // 0) f32 -> bf16 conversions
  cvt_f32_bf16<<<2048, 256, 0, stream>>>(x, xb, 4096 * 1024 / 4);
  cvt_f32_bf16<<<1536, 256, 0, stream>>>(qkv_w, wqkvb, 3072 * 1024 / 4);
  cvt_f32_bf16<<<512, 256, 0, stream>>>(proj_w, wprojb, 1024 * 1024 / 4);

  // 1) qkv = x @ qkv_w^T   (M=4096, N=3072, K=1024), bf16 out
  gemm_nt<0, 1><<<dim3(3072 / 128, 4096 / 128), 256, 0, stream>>>(
      xb, wqkvb, nullptr, qkv, 4096, 3072, 1024);

  // 2a) rmsnorm + rotary on Q,K (65536 (t,h) waves)
  rope_norm<<<65536 / 4, 256, 0, stream>>>(qkv, q_norm_w, k_norm_w, pos_cos,
                                           pos_sin, Qb, Kb);
  // 2b) V transpose to [bh][d][n]
  vtrans<<<dim3(32, 32), 256, 0, stream>>>(qkv, Vt);

  // 3) causal flash attention v3: 32 bh x 16 balanced tile-pairs, 4 waves
  attn_flash<<<dim3(32, 16), 256, 0, stream>>>(Qb, Kb, Vt, AO);

  // 4) out = AO @ proj_w^T + proj_b  (M=4096, N=1024, K=1024), f32 out
  gemm_nt<1, 0><<<dim3(1024 / 128, 4096 / 128), 256, 0, stream>>>(
      AO, wprojb, proj_b, (float*)d_out, 4096, 1024, 1024);
}

// Round 5
// 223.162 us; speedup vs baseline: 1.7086x; 1.0450x over previous
//
#include <hip/hip_runtime.h>

using u16 = unsigned short;
using short8 = __attribute__((ext_vector_type(8))) short;
using floatx4 = __attribute__((ext_vector_type(4))) float;

__device__ __forceinline__ float bf2f(u16 h) {
  union { unsigned int u; float f; } v;
  v.u = ((unsigned int)h) << 16;
  return v.f;
}
__device__ __forceinline__ u16 f2bf(float f) {
  union { float f; unsigned int u; } v;
  v.f = f;
  unsigned int u = v.u;
  return (u16)((u + 0x7FFFu + ((u >> 16) & 1u)) >> 16);
}
__device__ __forceinline__ u16 f2bf_rtz(float f) {  // truncate: 1 op
  union { float f; unsigned int u; } v;
  v.f = f;
  return (u16)(v.u >> 16);
}

// async global->LDS 16B copy (dest must be uniform base + lane*16)
typedef const __attribute__((address_space(1))) unsigned int* gas_t;
typedef __attribute__((address_space(3))) unsigned int* las_t;
__device__ __forceinline__ void gl_lds16(const u16* g, u16* l) {
  __builtin_amdgcn_global_load_lds((gas_t)(const void*)g, (las_t)(void*)l, 16,
                                   0, 0);
}

// ---------------------------------------------------------------------------
// f32 -> bf16 (RNE) convert, vectorized x4, grid-stride
// ---------------------------------------------------------------------------
__global__ __launch_bounds__(256) void cvt_f32_bf16(
    const float* __restrict__ in, u16* __restrict__ out, int n4) {
  for (int i = blockIdx.x * blockDim.x + threadIdx.x; i < n4;
       i += gridDim.x * blockDim.x) {
    float4 v = ((const float4*)in)[i];
    ushort4 o;
    o.x = f2bf(v.x);
    o.y = f2bf(v.y);
    o.z = f2bf(v.z);
    o.w = f2bf(v.w);
    ((ushort4*)out)[i] = o;
  }
}

// ---------------------------------------------------------------------------
// NT GEMM, m97 structure: C[M,N] = A[M,K] @ B[N,K]^T, bf16 in, fp32 acc.
// 128x128 block tile, BK=32, global_load_lds(16B) staging, 4 waves,
// wave tile 64x64 = 4x4 x mfma_16x16x32.
// ---------------------------------------------------------------------------
template <int BIAS, int OUTBF16>
__global__ __launch_bounds__(256) void gemm_nt(
    const u16* __restrict__ A, const u16* __restrict__ B,
    const float* __restrict__ bias, void* __restrict__ Cout,
    int M, int N, int K) {
  __shared__ u16 As[128 * 32];
  __shared__ u16 Bs[128 * 32];
  const int tid = threadIdx.x;
  const int lane = tid & 63;
  const int wave = tid >> 6;
  const int col = lane & 15;
  const int quad = lane >> 4;
  const int bm = blockIdx.y * 128;
  const int bn = blockIdx.x * 128;
  const int wm = (wave >> 1) * 64;
  const int wn = (wave & 1) * 64;

  floatx4 acc[4][4] = {};

  for (int kb = 0; kb < K; kb += 32) {
    __syncthreads();  // previous fragment reads done
#pragma unroll
    for (int i = 0; i < 2; i++) {
      const int c = i * 256 + tid;      // chunk: row=c>>2, 16B piece=c&3
      const int row = c >> 2;
      const int kc = (c & 3) * 8;
      gl_lds16(A + (size_t)(bm + row) * K + kb + kc, (u16*)As + c * 8);
      gl_lds16(B + (size_t)(bn + row) * K + kb + kc, (u16*)Bs + c * 8);
    }
    __syncthreads();  // fills visible

    short8 af[4], bfr[4];
#pragma unroll
    for (int i = 0; i < 4; i++)
      af[i] = *(const short8*)(As + (wm + i * 16 + col) * 32 + quad * 8);
#pragma unroll
    for (int i = 0; i < 4; i++)
      bfr[i] = *(const short8*)(Bs + (wn + i * 16 + col) * 32 + quad * 8);
#pragma unroll
    for (int mi = 0; mi < 4; mi++)
#pragma unroll
      for (int ni = 0; ni < 4; ni++)
        acc[mi][ni] = __builtin_amdgcn_mfma_f32_16x16x32_bf16(
            af[mi], bfr[ni], acc[mi][ni], 0, 0, 0);
  }

#pragma unroll
  for (int mi = 0; mi < 4; mi++) {
#pragma unroll
    for (int ni = 0; ni < 4; ni++) {
#pragma unroll
      for (int r = 0; r < 4; r++) {
        int row = bm + wm + mi * 16 + quad * 4 + r;
        int c = bn + wn + ni * 16 + col;
        float v = acc[mi][ni][r];
        if (BIAS) v += bias[c];
        if (OUTBF16)
          ((u16*)Cout)[(size_t)row * N + c] = f2bf(v);
        else
          ((float*)Cout)[(size_t)row * N + c] = v;
      }
    }
  }
}

// ---------------------------------------------------------------------------
// RMSNorm + rotary for Q,K only. One wave per (token, head); lane = dim.
// ---------------------------------------------------------------------------
__global__ __launch_bounds__(256) void rope_norm(
    const u16* __restrict__ qkv, const float* __restrict__ qw,
    const float* __restrict__ kw, const float* __restrict__ pcos,
    const float* __restrict__ psin, u16* __restrict__ Qb,
    u16* __restrict__ Kb) {
  const int w = blockIdx.x * 4 + (threadIdx.x >> 6);  // (t,h) id: 0..65535
  const int lane = threadIdx.x & 63;
  const int t = w >> 4;
  const int h = w & 15;
  const int n = t & 2047;
  const int b = t >> 11;

  const u16* base = qkv + (size_t)t * 3072 + h * 64 + lane;
  float qv = bf2f(base[0]);
  float kv = bf2f(base[1024]);

  float sq = qv * qv, sk = kv * kv;
#pragma unroll
  for (int off = 32; off; off >>= 1) {
    sq += __shfl_xor(sq, off);
    sk += __shfl_xor(sk, off);
  }
  float qn = qv * rsqrtf(sq * (1.0f / 64.0f) + 1e-6f) * qw[lane];
  float kn = kv * rsqrtf(sk * (1.0f / 64.0f) + 1e-6f) * kw[lane];

  const int i = lane >> 1;
  const float c = pcos[n * 32 + i];
  const float s = psin[n * 32 + i];
  float qp = __shfl_xor(qn, 1);
  float kp = __shfl_xor(kn, 1);
  float qr, kr;
  if (lane & 1) {
    qr = qp * s + qn * c;
    kr = kp * s + kn * c;
  } else {
    qr = qn * c - qp * s;
    kr = kn * c - kp * s;
  }
  qr *= 0.125f;  // fold attention scale hd^-0.5 into Q

  const size_t o = ((size_t)(b * 16 + h) * 2048 + n) * 64 + lane;
  Qb[o] = f2bf(qr);
  Kb[o] = f2bf(kr);
}

// ---------------------------------------------------------------------------
// V transpose: qkv V-slice [token][d] -> Vt [bh][d][n], 64x64 LDS tiles,
// coalesced 128B rows both directions.
// ---------------------------------------------------------------------------
__global__ __launch_bounds__(256) void vtrans(const u16* __restrict__ qkv,
                                              u16* __restrict__ Vt) {
  __shared__ u16 T[64 * 68];
  const int bh = blockIdx.x;  // b*16+h
  const int n0 = blockIdx.y * 64;
  const int b = bh >> 4, h = bh & 15;
  const int tid = threadIdx.x;
  const int q = tid & 7;   // 16B chunk within a 128B row
  const int r = tid >> 3;  // 0..31

#pragma unroll
  for (int rr = r; rr < 64; rr += 32) {
    short8 v = *(const short8*)(qkv + (size_t)(b * 2048 + n0 + rr) * 3072 +
                                2048 + h * 64 + q * 8);
    *(short8*)&T[rr * 68 + q * 8] = v;
  }
  __syncthreads();
#pragma unroll
  for (int dd = r; dd < 64; dd += 32) {
    short8 o;
#pragma unroll
    for (int j = 0; j < 8; j++) o[j] = T[(q * 8 + j) * 68 + dd];
    *(short8*)(Vt + (size_t)(bh * 64 + dd) * 2048 + n0 + q * 8) = o;
  }
}

// ---------------------------------------------------------------------------
// Flash attention v4 (causal). Block = 4 waves = 64 q-rows = one q-tile.
// Grid 1024 blocks, biggest tile first (load-balance via dispatch order);
// ~4-6 blocks/CU resident (25KB LDS) for latency hiding. K/V staged via
// global_load_lds. Fixed-max softmax (|s|<=8.1): p=exp(s-16), no running
// max. Unmasked fast path for interior key tiles; RTZ bf16 pack for P.
// 2 barriers/step (P round-trip is wave-private).
// ---------------------------------------------------------------------------
__global__ __launch_bounds__(256) void attn_flash(
    const u16* __restrict__ Q, const u16* __restrict__ Kk,
    const u16* __restrict__ Vt, u16* __restrict__ O) {
  __shared__ u16 Ks[2][64 * 32];  // [d-half][key][32d]
  __shared__ u16 Vs[2][64 * 32];  // [key-half][d][32keys]
  __shared__ u16 Pb[4][16 * 68];  // per-wave P round-trip
  const int id = blockIdx.x;
  const int bh = id & 31;
  const int tile = 31 - (id >> 5);  // big tiles dispatch first
  const int tid = threadIdx.x;
  const int lane = tid & 63;
  const int wave = tid >> 6;
  const int col = lane & 15;
  const int quad = lane >> 4;
  const int srow = tid >> 2;      // staging: row 0..63
  const int spc = (tid & 3) * 8;  // staging: 16B piece

  const u16* Qh = Q + (size_t)bh * 2048 * 64;
  const u16* Kh = Kk + (size_t)bh * 2048 * 64;
  const u16* Vh = Vt + (size_t)bh * 64 * 2048;
  const int b = bh >> 4, h = bh & 15;

  const int q0 = tile * 64 + wave * 16;  // this wave's 16 q-rows

  short8 aq[2];
#pragma unroll
  for (int ks = 0; ks < 2; ks++)
    aq[ks] = *(const short8*)(Qh + (size_t)(q0 + col) * 64 + ks * 32 + quad * 8);

  floatx4 accO[4] = {};
  float l[4] = {0.f, 0.f, 0.f, 0.f};
  const int nsteps = tile + 1;

  for (int kt = 0; kt < nsteps; kt++) {
    const int j0 = kt * 64;
    __syncthreads();  // prior step's K/V reads done (all waves)
#pragma unroll
    for (int half = 0; half < 2; half++) {
      gl_lds16(Kh + (size_t)(j0 + srow) * 64 + half * 32 + spc,
               &Ks[half][0] + tid * 8);
      gl_lds16(Vh + (size_t)srow * 2048 + j0 + half * 32 + spc,
               &Vs[half][0] + tid * 8);
    }
    __syncthreads();  // fills visible

    // S = Q K^T : 8 MFMA covering 16 q x 64 keys
    floatx4 s[4] = {};
#pragma unroll
    for (int nt = 0; nt < 4; nt++) {
#pragma unroll
      for (int ks = 0; ks < 2; ks++) {
        short8 bk = *(const short8*)&Ks[ks][(nt * 16 + col) * 32 + quad * 8];
        s[nt] =
            __builtin_amdgcn_mfma_f32_16x16x32_bf16(aq[ks], bk, s[nt], 0, 0, 0);
      }
    }

    // p = exp(s-16); causal mask only on the diagonal tile (wave-uniform)
    if (j0 + 63 <= q0) {  // fully unmasked fast path
#pragma unroll
      for (int nt = 0; nt < 4; nt++) {
#pragma unroll
        for (int r = 0; r < 4; r++) {
          float pv = __expf(s[nt][r] - 16.0f);
          l[r] += pv;
          Pb[wave][(quad * 4 + r) * 68 + nt * 16 + col] = f2bf_rtz(pv);
        }
      }
    } else {
#pragma unroll
      for (int nt = 0; nt < 4; nt++) {
        const int jg = j0 + nt * 16 + col;
#pragma unroll
        for (int r = 0; r < 4; r++) {
          const int qg = q0 + quad * 4 + r;
          float pv = (jg <= qg) ? __expf(s[nt][r] - 16.0f) : 0.0f;
          l[r] += pv;
          Pb[wave][(quad * 4 + r) * 68 + nt * 16 + col] = f2bf_rtz(pv);
        }
      }
    }
    // no barrier: Pb[wave] is wave-private, lgkmcnt orders write->read

    short8 ap[2];
#pragma unroll
    for (int kf = 0; kf < 2; kf++)
      ap[kf] = *(const short8*)&Pb[wave][col * 68 + kf * 32 + quad * 8];
#pragma unroll
    for (int nt = 0; nt < 4; nt++) {
#pragma unroll
      for (int kf = 0; kf < 2; kf++) {
        short8 bv = *(const short8*)&Vs[kf][(nt * 16 + col) * 32 + quad * 8];
        accO[nt] =
            __builtin_amdgcn_mfma_f32_16x16x32_bf16(ap[kf], bv, accO[nt], 0, 0, 0);
      }
    }
  }

  // final row-sum reduction across the 16 cols
#pragma unroll
  for (int r = 0; r < 4; r++) {
#pragma unroll
    for (int off = 8; off; off >>= 1) l[r] += __shfl_xor(l[r], off);
  }

  // epilogue: O token-major [b][n][h][d] feeding the proj GEMM
#pragma unroll
  for (int nt = 0; nt < 4; nt++) {
#pragma unroll
    for (int r = 0; r < 4; r++) {
      int qg = q0 + quad * 4 + r;
      int d = nt * 16 + col;
      O[((size_t)(b * 2048 + qg) * 16 + h) * 64 + d] = f2bf(accO[nt][r] / l[r]);
    }
  }
}

// ---------------------------------------------------------------------------
extern "C" void kernel_launch(void* const* d_in, const int* in_sizes, int n_in,
                              void* d_out, int out_size, void* d_ws,
                              size_t ws_size, hipStream_t stream) {
  const float* x = (const float*)d_in[0];        // [2,2048,1024] f32
  const float* qkv_w = (const float*)d_in[1];    // [3072,1024] f32
  const float* q_norm_w = (const float*)d_in[2]; // [64] f32
  const float* k_norm_w = (const float*)d_in[3]; // [64] f32
  const float* proj_w = (const float*)d_in[4];   // [1024,1024] f32
  const float* proj_b = (const float*)d_in[5];   // [1024] f32
  const float* pos_cos = (const float*)d_in[6];  // [2048,32] f32
  const float* pos_sin = (const float*)d_in[7];  // [2048,32] f32
  // d_in[8] = causal mask: known analytically, ignored

  char* ws = (char*)d_ws;
  u16* xb = (u16*)ws;                          //  8 MB (4096*1024 bf16)
  u16* wqkvb = (u16*)(ws + 8388608);           //  6 MB (3072*1024 bf16)
  u16* wprojb = (u16*)(ws + 14680064);         //  2 MB (1024*1024 bf16)
  u16* qkv = (u16*)(ws + 16777216);            // 24 MB (4096*3072 bf16)
  u16* Qb = (u16*)(ws + 41943040);             //  8 MB
  u16* Kb = (u16*)(ws + 50331648);             //  8 MB
  u16* Vt = (u16*)(ws + 58720256);             //  8 MB
  u16* AO = (u16*)(ws + 67108864);             //  8 MB  (total 72 MB)

  // 0) f32 -> bf16 conversions
  cvt_f32_bf16<<<2048, 256, 0, stream>>>(x, xb, 4096 * 1024 / 4);
  cvt_f32_bf16<<<1536, 256, 0, stream>>>(qkv_w, wqkvb, 3072 * 1024 / 4);
  cvt_f32_bf16<<<512, 256, 0, stream>>>(proj_w, wprojb, 1024 * 1024 / 4);

  // 1) qkv = x @ qkv_w^T   (M=4096, N=3072, K=1024), bf16 out
  gemm_nt<0, 1><<<dim3(3072 / 128, 4096 / 128), 256, 0, stream>>>(
      xb, wqkvb, nullptr, qkv, 4096, 3072, 1024);

  // 2a) rmsnorm + rotary on Q,K (65536 (t,h) waves)
  rope_norm<<<65536 / 4, 256, 0, stream>>>(qkv, q_norm_w, k_norm_w, pos_cos,
                                           pos_sin, Qb, Kb);
  // 2b) V transpose to [bh][d][n]
  vtrans<<<dim3(32, 32), 256, 0, stream>>>(qkv, Vt);

  // 3) causal flash attention v4: 1024 blocks, big tiles first
  attn_flash<<<dim3(1024), 256, 0, stream>>>(Qb, Kb, Vt, AO);

  // 4) out = AO @ proj_w^T + proj_b  (M=4096, N=1024, K=1024), f32 out
  gemm_nt<1, 0><<<dim3(1024 / 128, 4096 / 128), 256, 0, stream>>>(
      AO, wprojb, proj_b, (float*)d_out, 4096, 1024, 1024);
}